// Round 1
// baseline (2726.941 us; speedup 1.0000x reference)
//
#include <hip/hip_runtime.h>

#define CIN 8
#define COUT 32
#define NR 2
#define EPSF 1e-6f

// Q layout: Q[n][c] with c = (r*CIN + i)*2 + k   (32 floats per node)

__global__ __launch_bounds__(256) void lift_edge_kernel(
    const float* __restrict__ x,         // [N, CIN]
    const int*   __restrict__ edge_index,// [2, E] (row0 = src, row1 = dst)
    const float* __restrict__ pcmp,      // [E, NR, 2]
    float*       __restrict__ Q,         // [N, 32], zero-initialized
    int E)
{
    int e = blockIdx.x * 256 + threadIdx.x;
    if (e >= E) return;
    int s = edge_index[e];
    int d = edge_index[E + e];
    float4 pc = *reinterpret_cast<const float4*>(pcmp + (size_t)e * 4);
    const float4* xp = reinterpret_cast<const float4*>(x + (size_t)s * CIN);
    float4 x0 = xp[0], x1 = xp[1];
    float xv[8] = {x0.x, x0.y, x0.z, x0.w, x1.x, x1.y, x1.z, x1.w};
    float* qn = Q + (size_t)d * 32;
#pragma unroll
    for (int i = 0; i < 8; ++i) {
        atomicAdd(qn + i * 2 + 0,      xv[i] * pc.x);  // r=0, k=0
        atomicAdd(qn + i * 2 + 1,      xv[i] * pc.y);  // r=0, k=1
        atomicAdd(qn + 16 + i * 2 + 0, xv[i] * pc.z);  // r=1, k=0
        atomicAdd(qn + 16 + i * 2 + 1, xv[i] * pc.w);  // r=1, k=1
    }
}

__global__ __launch_bounds__(256) void lift_node_kernel(
    const float* __restrict__ Q,      // [N, 32]
    const float* __restrict__ W_rad,  // [NR, CIN, COUT] = [16, 32] flat
    const float* __restrict__ phase,  // [COUT]
    const float* __restrict__ b_nl,   // [COUT]
    const float* __restrict__ W1, const float* __restrict__ b1,
    const float* __restrict__ W2, const float* __restrict__ b2,
    const float* __restrict__ W3, const float* __restrict__ b3,
    float* __restrict__ out,          // [N, COUT, 2]
    int N)
{
    __shared__ float sWrad[NR * CIN][COUT];   // 2 KB
    __shared__ float sW[3][COUT][COUT];       // 12 KB
    __shared__ float ybuf[2][8][COUT][2];     // 4 KB

    for (int idx = threadIdx.x; idx < NR * CIN * COUT; idx += 256)
        sWrad[idx >> 5][idx & 31] = W_rad[idx];
    for (int idx = threadIdx.x; idx < COUT * COUT; idx += 256) {
        sW[0][idx >> 5][idx & 31] = W1[idx];
        sW[1][idx >> 5][idx & 31] = W2[idx];
        sW[2][idx >> 5][idx & 31] = W3[idx];
    }
    __syncthreads();

    const int o  = threadIdx.x & 31;   // output channel
    const int nl = threadIdx.x >> 5;   // node slot within block (0..7)
    const int n  = blockIdx.x * 8 + nl;
    const bool active = (n < N);

    if (active) {
        const float* qn = Q + (size_t)n * 32;
        float a0 = 0.f, a1 = 0.f;
#pragma unroll
        for (int ri = 0; ri < NR * CIN; ++ri) {
            float w = sWrad[ri][o];
            a0 += w * qn[ri * 2 + 0];
            a1 += w * qn[ri * 2 + 1];
        }
        // learned phase rotation
        float sn, cs;
        __sincosf(phase[o], &sn, &cs);
        float re = a0 * cs - a1 * sn;
        float im = a0 * sn + a1 * cs;
        // TangentNonLin
        float mag = sqrtf(re * re + im * im + EPSF);
        float sc  = fmaxf(mag + b_nl[o], 0.f) / mag;
        ybuf[0][nl][o][0] = re * sc;
        ybuf[0][nl][o][1] = im * sc;
    }
    __syncthreads();

    const float* bias[3] = {b1, b2, b3};
    int cur = 0;
#pragma unroll
    for (int layer = 0; layer < 3; ++layer) {
        if (active) {
            float a0 = 0.f, a1 = 0.f;
#pragma unroll
            for (int i = 0; i < COUT; ++i) {
                float w = sW[layer][i][o];
                a0 += w * ybuf[cur][nl][i][0];
                a1 += w * ybuf[cur][nl][i][1];
            }
            float mag = sqrtf(a0 * a0 + a1 * a1 + EPSF);
            float sc  = fmaxf(mag + bias[layer][o], 0.f) / mag;
            ybuf[cur ^ 1][nl][o][0] = a0 * sc;
            ybuf[cur ^ 1][nl][o][1] = a1 * sc;
        }
        __syncthreads();
        cur ^= 1;
    }

    if (active) {
        float2 v;
        v.x = ybuf[cur][nl][o][0];
        v.y = ybuf[cur][nl][o][1];
        *reinterpret_cast<float2*>(out + ((size_t)n * COUT + o) * 2) = v;
    }
}

extern "C" void kernel_launch(void* const* d_in, const int* in_sizes, int n_in,
                              void* d_out, int out_size, void* d_ws, size_t ws_size,
                              hipStream_t stream)
{
    const float* x     = (const float*)d_in[0];
    const int*   eidx  = (const int*)  d_in[1];
    const float* pcmp  = (const float*)d_in[2];
    const float* W_rad = (const float*)d_in[3];
    const float* phase = (const float*)d_in[4];
    const float* b_nl  = (const float*)d_in[5];
    const float* W1    = (const float*)d_in[6];
    const float* b1    = (const float*)d_in[7];
    const float* W2    = (const float*)d_in[8];
    const float* b2    = (const float*)d_in[9];
    const float* W3    = (const float*)d_in[10];
    const float* b3    = (const float*)d_in[11];
    float* out = (float*)d_out;

    const int N = in_sizes[0] / CIN;
    const int E = in_sizes[1] / 2;

    float* Q = (float*)d_ws;
    hipMemsetAsync(Q, 0, (size_t)N * 32 * sizeof(float), stream);

    lift_edge_kernel<<<(E + 255) / 256, 256, 0, stream>>>(x, eidx, pcmp, Q, E);
    lift_node_kernel<<<(N + 7) / 8, 256, 0, stream>>>(
        Q, W_rad, phase, b_nl, W1, b1, W2, b2, W3, b3, out, N);
}

// Round 2
// 312.727 us; speedup vs baseline: 8.7199x; 8.7199x over previous
//
#include <hip/hip_runtime.h>

#define CIN 8
#define COUT 32
#define NR 2
#define EPSF 1e-6f
#define SCAN_BS 512

// ---------------- pass 1: histogram of dst ----------------
__global__ __launch_bounds__(256) void hist_kernel(
    const int* __restrict__ edge_index, int* __restrict__ counts, int E)
{
    int e = blockIdx.x * 256 + threadIdx.x;
    if (e < E) atomicAdd(&counts[edge_index[E + e]], 1);
}

// ---------------- pass 2: exclusive scan (3 kernels) ----------------
__global__ __launch_bounds__(SCAN_BS) void scan1_kernel(
    const int* __restrict__ counts, int* __restrict__ offsets,
    int* __restrict__ bsums, int N)
{
    __shared__ int sh[SCAN_BS];
    int j = blockIdx.x * SCAN_BS + threadIdx.x;
    sh[threadIdx.x] = (j < N) ? counts[j] : 0;
    __syncthreads();
#pragma unroll
    for (int off = 1; off < SCAN_BS; off <<= 1) {
        int t = (threadIdx.x >= off) ? sh[threadIdx.x - off] : 0;
        __syncthreads();
        sh[threadIdx.x] += t;
        __syncthreads();
    }
    if (j < N) offsets[j + 1] = sh[threadIdx.x];
    if (threadIdx.x == SCAN_BS - 1) bsums[blockIdx.x] = sh[threadIdx.x];
    if (j == 0) offsets[0] = 0;
}

__global__ __launch_bounds__(256) void scan2_kernel(int* __restrict__ bsums, int nb)
{
    __shared__ int sh[256];
    int t = threadIdx.x;
    sh[t] = (t < nb) ? bsums[t] : 0;
    __syncthreads();
#pragma unroll
    for (int off = 1; off < 256; off <<= 1) {
        int v = (t >= off) ? sh[t - off] : 0;
        __syncthreads();
        sh[t] += v;
        __syncthreads();
    }
    if (t < nb) bsums[t] = (t == 0) ? 0 : sh[t - 1];   // exclusive
}

__global__ __launch_bounds__(SCAN_BS) void scan3_kernel(
    int* __restrict__ offsets, const int* __restrict__ bsums, int N)
{
    int j = blockIdx.x * SCAN_BS + threadIdx.x;
    if (j < N) offsets[j + 1] += bsums[blockIdx.x];
}

// ---------------- pass 3: scatter edge ids into dst buckets ----------------
__global__ __launch_bounds__(256) void fill_kernel(
    const int* __restrict__ edge_index, int* __restrict__ cursor,
    int* __restrict__ sorted_id, int E)
{
    int e = blockIdx.x * 256 + threadIdx.x;
    if (e >= E) return;
    int d = edge_index[E + e];
    int pos = atomicAdd(&cursor[d], 1);
    sorted_id[pos] = e;
}

// ---------------- pass 4: fused gather + field conv + MLP ----------------
__global__ __launch_bounds__(256) void fused_node_kernel(
    const float* __restrict__ x,          // [N, CIN]
    const int*   __restrict__ edge_index, // [2, E]
    const float* __restrict__ pcmp,       // [E, NR, 2]
    const int*   __restrict__ offsets,    // [N+1]
    const int*   __restrict__ sorted_id,  // [E]
    const float* __restrict__ W_rad,      // [NR*CIN, COUT]
    const float* __restrict__ phase,
    const float* __restrict__ b_nl,
    const float* __restrict__ W1, const float* __restrict__ b1,
    const float* __restrict__ W2, const float* __restrict__ b2,
    const float* __restrict__ W3, const float* __restrict__ b3,
    float* __restrict__ out,              // [N, COUT, 2]
    int N)
{
    __shared__ float sWrad[NR * CIN][COUT];   // 2 KB
    __shared__ float sW[3][COUT][COUT];       // 12 KB
    __shared__ float qbuf[8][32];             // 1 KB
    __shared__ float ybuf[2][8][COUT][2];     // 4 KB

    for (int idx = threadIdx.x; idx < NR * CIN * COUT; idx += 256)
        sWrad[idx >> 5][idx & 31] = W_rad[idx];
    for (int idx = threadIdx.x; idx < COUT * COUT; idx += 256) {
        sW[0][idx >> 5][idx & 31] = W1[idx];
        sW[1][idx >> 5][idx & 31] = W2[idx];
        sW[2][idx >> 5][idx & 31] = W3[idx];
    }

    const int c  = threadIdx.x & 31;   // Q channel  c = (r*8+i)*2+k
    const int g  = threadIdx.x >> 5;   // node slot in block (0..7)
    const int n  = blockIdx.x * 8 + g;
    const bool active = (n < N);

    // ---- per-channel gather-accumulate over this node's edge bucket ----
    float q = 0.f;
    if (active) {
        const int i_idx  = (c >> 1) & 7;            // x element
        const int pc_off = ((c >> 4) << 1) | (c & 1); // pcmp element
        int p   = offsets[n];
        int end = offsets[n + 1];
        for (; p + 1 < end; p += 2) {
            int id0 = sorted_id[p], id1 = sorted_id[p + 1];
            int s0 = edge_index[id0], s1 = edge_index[id1];
            float xa = x[(size_t)s0 * CIN + i_idx];
            float xb = x[(size_t)s1 * CIN + i_idx];
            float pa = pcmp[(size_t)id0 * 4 + pc_off];
            float pb = pcmp[(size_t)id1 * 4 + pc_off];
            q += xa * pa;
            q += xb * pb;
        }
        if (p < end) {
            int id0 = sorted_id[p];
            int s0 = edge_index[id0];
            q += x[(size_t)s0 * CIN + i_idx] * pcmp[(size_t)id0 * 4 + pc_off];
        }
        qbuf[g][c] = q;
    }
    __syncthreads();

    const int o = c;  // output channel for the epilogue
    if (active) {
        float a0 = 0.f, a1 = 0.f;
#pragma unroll
        for (int ri = 0; ri < NR * CIN; ++ri) {
            float w = sWrad[ri][o];
            a0 += w * qbuf[g][ri * 2 + 0];
            a1 += w * qbuf[g][ri * 2 + 1];
        }
        float sn, cs;
        __sincosf(phase[o], &sn, &cs);
        float re = a0 * cs - a1 * sn;
        float im = a0 * sn + a1 * cs;
        float mag = sqrtf(re * re + im * im + EPSF);
        float sc  = fmaxf(mag + b_nl[o], 0.f) / mag;
        ybuf[0][g][o][0] = re * sc;
        ybuf[0][g][o][1] = im * sc;
    }
    __syncthreads();

    const float* bias[3] = {b1, b2, b3};
    int cur = 0;
#pragma unroll
    for (int layer = 0; layer < 3; ++layer) {
        if (active) {
            float a0 = 0.f, a1 = 0.f;
#pragma unroll
            for (int i = 0; i < COUT; ++i) {
                float w = sW[layer][i][o];
                a0 += w * ybuf[cur][g][i][0];
                a1 += w * ybuf[cur][g][i][1];
            }
            float mag = sqrtf(a0 * a0 + a1 * a1 + EPSF);
            float sc  = fmaxf(mag + bias[layer][o], 0.f) / mag;
            ybuf[cur ^ 1][g][o][0] = a0 * sc;
            ybuf[cur ^ 1][g][o][1] = a1 * sc;
        }
        __syncthreads();
        cur ^= 1;
    }

    if (active) {
        float2 v;
        v.x = ybuf[cur][g][o][0];
        v.y = ybuf[cur][g][o][1];
        *reinterpret_cast<float2*>(out + ((size_t)n * COUT + o) * 2) = v;
    }
}

extern "C" void kernel_launch(void* const* d_in, const int* in_sizes, int n_in,
                              void* d_out, int out_size, void* d_ws, size_t ws_size,
                              hipStream_t stream)
{
    const float* x     = (const float*)d_in[0];
    const int*   eidx  = (const int*)  d_in[1];
    const float* pcmp  = (const float*)d_in[2];
    const float* W_rad = (const float*)d_in[3];
    const float* phase = (const float*)d_in[4];
    const float* b_nl  = (const float*)d_in[5];
    const float* W1    = (const float*)d_in[6];
    const float* b1    = (const float*)d_in[7];
    const float* W2    = (const float*)d_in[8];
    const float* b2    = (const float*)d_in[9];
    const float* W3    = (const float*)d_in[10];
    const float* b3    = (const float*)d_in[11];
    float* out = (float*)d_out;

    const int N = in_sizes[0] / CIN;
    const int E = in_sizes[1] / 2;

    // workspace layout (ints)
    int* counts  = (int*)d_ws;            // N
    int* offsets = counts + N;            // N+1
    int* bsums   = offsets + N + 1;       // 256
    int* cursor  = bsums + 256;           // N
    int* sorted  = cursor + N;            // E

    const int nb_scan = (N + SCAN_BS - 1) / SCAN_BS;

    hipMemsetAsync(counts, 0, (size_t)N * sizeof(int), stream);
    hist_kernel<<<(E + 255) / 256, 256, 0, stream>>>(eidx, counts, E);
    scan1_kernel<<<nb_scan, SCAN_BS, 0, stream>>>(counts, offsets, bsums, N);
    scan2_kernel<<<1, 256, 0, stream>>>(bsums, nb_scan);
    scan3_kernel<<<nb_scan, SCAN_BS, 0, stream>>>(offsets, bsums, N);
    hipMemcpyAsync(cursor, offsets, (size_t)N * sizeof(int),
                   hipMemcpyDeviceToDevice, stream);
    fill_kernel<<<(E + 255) / 256, 256, 0, stream>>>(eidx, cursor, sorted, E);
    fused_node_kernel<<<(N + 7) / 8, 256, 0, stream>>>(
        x, eidx, pcmp, offsets, sorted,
        W_rad, phase, b_nl, W1, b1, W2, b2, W3, b3, out, N);
}